// Round 2
// baseline (287.975 us; speedup 1.0000x reference)
//
#include <hip/hip_runtime.h>
#include <hip/hip_bf16.h>

// Problem constants
#define BB 2
#define TT 2048
#define DD 1024
#define HH 16
#define DH 64
#define RR 16
#define BT (BB*TT)      // 4096
#define BH (BB*HH)      // 32
#define D3 (3*DD)       // 3072

typedef __bf16 bf16x8 __attribute__((ext_vector_type(8)));
typedef float f32x4 __attribute__((ext_vector_type(4)));

__device__ __forceinline__ float bf2f(unsigned short u) {
  unsigned int v = ((unsigned int)u) << 16;
  return __builtin_bit_cast(float, v);
}
__device__ __forceinline__ unsigned short f2bf(float f) {
  unsigned int x = __builtin_bit_cast(unsigned int, f);
  unsigned int r = x + 0x7fffu + ((x >> 16) & 1u);
  return (unsigned short)(r >> 16);
}
__device__ __forceinline__ float rmax16(float v) {
#pragma unroll
  for (int off = 1; off < 16; off <<= 1) v = fmaxf(v, __shfl_xor(v, off, 64));
  return v;
}
__device__ __forceinline__ float rsum16(float v) {
#pragma unroll
  for (int off = 1; off < 16; off <<= 1) v += __shfl_xor(v, off, 64);
  return v;
}

#define NEG_BIG (-1e30f)

// ---------------- fp32 -> bf16 elementwise convert (n multiple of 8) ----------------
__global__ __launch_bounds__(256) void cvt_f32_bf16(const float* __restrict__ in,
                                                    unsigned short* __restrict__ out,
                                                    int n) {
  int i = (blockIdx.x * 256 + threadIdx.x) * 8;
  if (i >= n) return;
  float4 a = *(const float4*)&in[i];
  float4 b = *(const float4*)&in[i + 4];
  unsigned short t[8] = {f2bf(a.x), f2bf(a.y), f2bf(a.z), f2bf(a.w),
                         f2bf(b.x), f2bf(b.y), f2bf(b.z), f2bf(b.w)};
  *(uint4*)&out[i] = *(const uint4*)t;
}

// ---------------- transpose + convert: fp32 (R x C) -> bf16 (C x R) -----------------
__global__ __launch_bounds__(256) void transpose_cvt(const float* __restrict__ in,
                                                     unsigned short* __restrict__ out,
                                                     int R, int C) {
  __shared__ float tile[32][33];
  const int tx = threadIdx.x, ty = threadIdx.y;
  const int x = blockIdx.x * 32 + tx;
  const int y0 = blockIdx.y * 32;
#pragma unroll
  for (int i = 0; i < 32; i += 8)
    tile[ty + i][tx] = in[(size_t)(y0 + ty + i) * C + x];
  __syncthreads();
  const int xo = y0 + tx;
  const int yo0 = blockIdx.x * 32;
#pragma unroll
  for (int i = 0; i < 32; i += 8)
    out[(size_t)(yo0 + ty + i) * R + xo] = f2bf(tile[tx][ty + i]);
}

// ---------------- bf16 GEMM: C[MxN] = A[MxK] * Bt[NxK]^T ---------------------------
// 128x128 tile, BK=32, 256 threads = 4 waves in 2x2, 4x4 16x16 accs per wave.
// F32OUT: write float, else bf16.
template <bool F32OUT>
__global__ __launch_bounds__(256) void gemm_bt(const unsigned short* __restrict__ A,
                                               const unsigned short* __restrict__ Bt,
                                               void* __restrict__ Cv,
                                               int M, int N, int K) {
  __shared__ __attribute__((aligned(16))) unsigned short As[128 * 32];
  __shared__ __attribute__((aligned(16))) unsigned short Bs[128 * 32];
  const int tid = threadIdx.x;
  const int lane = tid & 63;
  const int g = lane >> 4, c = lane & 15;
  const int wid = tid >> 6;
  const int wm = wid >> 1, wn = wid & 1;
  const int bm = blockIdx.y, bn = blockIdx.x;

  f32x4 acc[4][4] = {};

  const int e0 = tid * 8, e1 = (256 + tid) * 8;
  const int r0 = e0 >> 5, q0 = e0 & 31;
  const int r1 = e1 >> 5, q1 = e1 & 31;

  for (int k0 = 0; k0 < K; k0 += 32) {
    uint4 a0 = *(const uint4*)&A[(size_t)(bm * 128 + r0) * K + k0 + q0];
    uint4 a1 = *(const uint4*)&A[(size_t)(bm * 128 + r1) * K + k0 + q1];
    uint4 b0 = *(const uint4*)&Bt[(size_t)(bn * 128 + r0) * K + k0 + q0];
    uint4 b1 = *(const uint4*)&Bt[(size_t)(bn * 128 + r1) * K + k0 + q1];
    __syncthreads();
    *(uint4*)&As[e0] = a0; *(uint4*)&As[e1] = a1;
    *(uint4*)&Bs[e0] = b0; *(uint4*)&Bs[e1] = b1;
    __syncthreads();
    bf16x8 af[4];
#pragma unroll
    for (int mt = 0; mt < 4; mt++)
      af[mt] = *(const bf16x8*)&As[(wm * 64 + mt * 16 + c) * 32 + g * 8];
#pragma unroll
    for (int nt = 0; nt < 4; nt++) {
      bf16x8 bf = *(const bf16x8*)&Bs[(wn * 64 + nt * 16 + c) * 32 + g * 8];
#pragma unroll
      for (int mt = 0; mt < 4; mt++)
        acc[mt][nt] = __builtin_amdgcn_mfma_f32_16x16x32_bf16(af[mt], bf, acc[mt][nt], 0, 0, 0);
    }
  }
#pragma unroll
  for (int mt = 0; mt < 4; mt++)
#pragma unroll
    for (int nt = 0; nt < 4; nt++)
#pragma unroll
      for (int r = 0; r < 4; r++) {
        int row = bm * 128 + wm * 64 + mt * 16 + g * 4 + r;
        int col = bn * 128 + wn * 64 + nt * 16 + c;
        if (F32OUT)
          ((float*)Cv)[(size_t)row * N + col] = acc[mt][nt][r];
        else
          ((unsigned short*)Cv)[(size_t)row * N + col] = f2bf(acc[mt][nt][r]);
      }
}

// ---------------- LSR repack: q_lr (scaled, padded), k_lr (padded), V^T -------------
// grid (T/64, B*H), 256 threads. qkv is (B*T, 3072) bf16; Wq/Wk/core are fp32.
__global__ __launch_bounds__(256) void lsr_repack(const unsigned short* __restrict__ qkv,
                                                  const float* __restrict__ Wq,
                                                  const float* __restrict__ Wk,
                                                  const float* __restrict__ core,
                                                  unsigned short* __restrict__ qls,  // (BH, T, 32)
                                                  unsigned short* __restrict__ klr,  // (BH, T, 32)
                                                  unsigned short* __restrict__ vt) { // (BH, 64, T)
  const int bh = blockIdx.y, b = bh >> 4, h = bh & 15;
  const int t0 = blockIdx.x * 64;
  const int tid = threadIdx.x;
  __shared__ float Wq_s[64 * 16], Wk_s[64 * 16], core_s[16];
  __shared__ unsigned short q_s[64 * 64], k_s[64 * 64], v_s[64 * 64];

  for (int i = tid; i < 1024; i += 256) {
    Wq_s[i] = Wq[h * 1024 + i];
    Wk_s[i] = Wk[h * 1024 + i];
  }
  if (tid < 16) core_s[tid] = core[h * 16 + tid];
#pragma unroll
  for (int p = 0; p < 2; p++) {
    int e = (p * 256 + tid) * 8;
    int t = e >> 6, d = e & 63;
    size_t base = ((size_t)(b * TT + t0 + t)) * D3 + h * 64 + d;
    *(uint4*)&q_s[e] = *(const uint4*)&qkv[base];
    *(uint4*)&k_s[e] = *(const uint4*)&qkv[base + DD];
    *(uint4*)&v_s[e] = *(const uint4*)&qkv[base + 2 * DD];
  }
  __syncthreads();

#pragma unroll
  for (int itr = 0; itr < 4; itr++) {
    int idx = itr * 256 + tid;           // 0..1023
    int t = idx >> 4, r = idx & 15;
    float aq = 0.f, ak = 0.f;
#pragma unroll
    for (int d = 0; d < 64; d++) {
      aq += bf2f(q_s[t * 64 + d]) * Wq_s[d * 16 + r];
      ak += bf2f(k_s[t * 64 + d]) * Wk_s[d * 16 + r];
    }
    aq *= core_s[r] * 0.25f;             // core * 1/sqrt(R)
    size_t ob = ((size_t)bh * TT + t0 + t) * 32;
    qls[ob + r] = f2bf(aq);
    qls[ob + 16 + r] = 0;                // zero pad r=16..31
    klr[ob + r] = f2bf(ak);
    klr[ob + 16 + r] = 0;
  }
#pragma unroll
  for (int p = 0; p < 16; p++) {
    int idx = p * 256 + tid;             // 0..4095
    int d = idx >> 6, t = idx & 63;
    vt[((size_t)bh * 64 + d) * TT + t0 + t] = v_s[t * 64 + d];
  }
}

// ---------------- Flash attention over low-rank scores ------------------------------
// grid (T/128, B*H), 256 threads. Wave w owns query rows [w*32, w*32+32).
__global__ __launch_bounds__(256) void flash_lsr(const unsigned short* __restrict__ qls,
                                                 const unsigned short* __restrict__ klr,
                                                 const unsigned short* __restrict__ vt,
                                                 unsigned short* __restrict__ attn) { // (B*T, 1024)
  const int it = blockIdx.x;
  const int bh = blockIdx.y, b = bh >> 4, h = bh & 15;
  const int tid = threadIdx.x, lane = tid & 63, w = tid >> 6;
  const int g = lane >> 4, c = lane & 15;
  const int q0 = it * 128;
  __shared__ __attribute__((aligned(16))) unsigned short Ks[128 * 32];   // 8KB
  __shared__ __attribute__((aligned(16))) unsigned short Vs[64 * 136];   // padded stride
  __shared__ __attribute__((aligned(16))) unsigned short Ps[128 * 136];  // padded stride

  bf16x8 qf[2];
#pragma unroll
  for (int mt = 0; mt < 2; mt++) {
    int row = q0 + w * 32 + mt * 16 + c;
    qf[mt] = *(const bf16x8*)&qls[((size_t)bh * TT + row) * 32 + g * 8];
  }
  float mi[2][4], li[2][4];
  f32x4 oa[2][4] = {};
#pragma unroll
  for (int mt = 0; mt < 2; mt++)
#pragma unroll
    for (int r = 0; r < 4; r++) { mi[mt][r] = NEG_BIG; li[mt][r] = 0.f; }

  const f32x4 zero = {0.f, 0.f, 0.f, 0.f};

  for (int jt = 0; jt <= it; jt++) {
    {
      const uint4* src = (const uint4*)&klr[((size_t)bh * TT + jt * 128) * 32];
      *(uint4*)&Ks[tid * 8] = src[tid];
      *(uint4*)&Ks[(256 + tid) * 8] = src[256 + tid];
    }
#pragma unroll
    for (int p = 0; p < 4; p++) {
      int e = (p * 256 + tid) * 8;
      int d = e >> 7, te = e & 127;
      *(uint4*)&Vs[d * 136 + te] = *(const uint4*)&vt[((size_t)bh * 64 + d) * TT + jt * 128 + te];
    }
    __syncthreads();

#pragma unroll
    for (int mt = 0; mt < 2; mt++) {
      f32x4 s[8];
#pragma unroll
      for (int nt = 0; nt < 8; nt++) {
        bf16x8 bfr = *(const bf16x8*)&Ks[(nt * 16 + c) * 32 + g * 8];
        s[nt] = __builtin_amdgcn_mfma_f32_16x16x32_bf16(qf[mt], bfr, zero, 0, 0, 0);
      }
      if (jt == it) {
#pragma unroll
        for (int nt = 0; nt < 8; nt++)
#pragma unroll
          for (int r = 0; r < 4; r++) {
            int col = nt * 16 + c;
            int row = w * 32 + mt * 16 + g * 4 + r;
            if (col > row) s[nt][r] = NEG_BIG;
          }
      }
#pragma unroll
      for (int r = 0; r < 4; r++) {
        float rm = s[0][r];
#pragma unroll
        for (int nt = 1; nt < 8; nt++) rm = fmaxf(rm, s[nt][r]);
        rm = rmax16(rm);
        float mo = mi[mt][r];
        float mnew = fmaxf(mo, rm);
        float alpha = __expf(mo - mnew);   // exp(-huge)=0 on first tile
        mi[mt][r] = mnew;
        float rs = 0.f;
#pragma unroll
        for (int nt = 0; nt < 8; nt++) {
          float pv = __expf(s[nt][r] - mnew);
          s[nt][r] = pv;
          rs += pv;
        }
        rs = rsum16(rs);
        li[mt][r] = li[mt][r] * alpha + rs;
#pragma unroll
        for (int nd = 0; nd < 4; nd++) oa[mt][nd][r] *= alpha;
        int prow = w * 32 + mt * 16 + g * 4 + r;  // wave-private rows: no barrier needed
#pragma unroll
        for (int nt = 0; nt < 8; nt++)
          Ps[prow * 136 + nt * 16 + c] = f2bf(s[nt][r]);
      }
    }

#pragma unroll
    for (int kk = 0; kk < 4; kk++) {
      bf16x8 af[2];
#pragma unroll
      for (int mt = 0; mt < 2; mt++)
        af[mt] = *(const bf16x8*)&Ps[(w * 32 + mt * 16 + c) * 136 + kk * 32 + g * 8];
#pragma unroll
      for (int nd = 0; nd < 4; nd++) {
        bf16x8 bfr = *(const bf16x8*)&Vs[(nd * 16 + c) * 136 + kk * 32 + g * 8];
#pragma unroll
        for (int mt = 0; mt < 2; mt++)
          oa[mt][nd] = __builtin_amdgcn_mfma_f32_16x16x32_bf16(af[mt], bfr, oa[mt][nd], 0, 0, 0);
      }
    }
    __syncthreads();
  }

#pragma unroll
  for (int mt = 0; mt < 2; mt++)
#pragma unroll
    for (int r = 0; r < 4; r++) {
      int row = q0 + w * 32 + mt * 16 + g * 4 + r;
      float inv = 1.f / li[mt][r];
#pragma unroll
      for (int nd = 0; nd < 4; nd++) {
        int col = h * 64 + nd * 16 + c;
        attn[((size_t)b * TT + row) * DD + col] = f2bf(oa[mt][nd][r] * inv);
      }
    }
}

extern "C" void kernel_launch(void* const* d_in, const int* in_sizes, int n_in,
                              void* d_out, int out_size, void* d_ws, size_t ws_size,
                              hipStream_t stream) {
  const float* x      = (const float*)d_in[0];  // (B,T,1024) fp32
  const float* W_qkv  = (const float*)d_in[1];  // (1024,3072) fp32
  const float* W_qlsr = (const float*)d_in[2];  // (16,64,16)  fp32
  const float* W_klsr = (const float*)d_in[3];  // (16,64,16)  fp32
  const float* core   = (const float*)d_in[4];  // (16,16)     fp32
  const float* W_o    = (const float*)d_in[5];  // (1024,1024) fp32
  float* out = (float*)d_out;                   // (B,T,1024)  fp32

  char* ws = (char*)d_ws;
  unsigned short* x_bf   = (unsigned short*)ws; ws += (size_t)BT * DD * 2;   // (4096,1024)
  unsigned short* Wqkv_t = (unsigned short*)ws; ws += (size_t)D3 * DD * 2;   // (3072,1024)
  unsigned short* Wo_t   = (unsigned short*)ws; ws += (size_t)DD * DD * 2;   // (1024,1024)
  unsigned short* qkv    = (unsigned short*)ws; ws += (size_t)BT * D3 * 2;   // (4096,3072)
  unsigned short* qls    = (unsigned short*)ws; ws += (size_t)BH * TT * 32 * 2;
  unsigned short* klr    = (unsigned short*)ws; ws += (size_t)BH * TT * 32 * 2;
  unsigned short* vt     = (unsigned short*)ws; ws += (size_t)BH * 64 * TT * 2;
  unsigned short* attn   = (unsigned short*)ws; ws += (size_t)BT * DD * 2;

  cvt_f32_bf16<<<(BT * DD) / (256 * 8), 256, 0, stream>>>(x, x_bf, BT * DD);
  transpose_cvt<<<dim3(D3 / 32, DD / 32), dim3(32, 8), 0, stream>>>(W_qkv, Wqkv_t, DD, D3);
  transpose_cvt<<<dim3(DD / 32, DD / 32), dim3(32, 8), 0, stream>>>(W_o, Wo_t, DD, DD);
  gemm_bt<false><<<dim3(D3 / 128, BT / 128), 256, 0, stream>>>(x_bf, Wqkv_t, qkv, BT, D3, DD);
  lsr_repack<<<dim3(TT / 64, BH), 256, 0, stream>>>(qkv, W_qlsr, W_klsr, core, qls, klr, vt);
  flash_lsr<<<dim3(TT / 128, BH), 256, 0, stream>>>(qls, klr, vt, attn);
  gemm_bt<true><<<dim3(DD / 128, BT / 128), 256, 0, stream>>>(attn, Wo_t, out, BT, DD, DD);
}